// Round 2
// baseline (119.960 us; speedup 1.0000x reference)
//
#include <hip/hip_runtime.h>
#include <math.h>

// Problem constants
#define B_  8
#define D_  128
#define L_  2048
#define H_  8
#define DH_ 16

#define LOG2E 1.4426950408889634f

typedef __bf16 bf16x8 __attribute__((ext_vector_type(8)));
typedef float  floatx4 __attribute__((ext_vector_type(4)));
typedef float  floatx16 __attribute__((ext_vector_type(16)));

#if __has_builtin(__builtin_amdgcn_exp2f)
#define EXP2(x) __builtin_amdgcn_exp2f(x)
#else
#define EXP2(x) exp2f(x)
#endif

// ---------------------------------------------------------------------------
// Weight pre-convert: fp32 W -> bf16 MFMA frag layout (lane idx = col,
// k = quad*8+j). tiles 0..7 = Q heads (W_q pre-scaled by DH^-0.5 * log2e so
// attn softmax is exp2(s)), 8..15 = K, 16..23 = V.
// ---------------------------------------------------------------------------
__global__ __launch_bounds__(256) void wconv_kernel(
    const float* __restrict__ wmem, const float* __restrict__ wq,
    __bf16* __restrict__ Wb) {
  const int tile = blockIdx.x;
  const int tid = threadIdx.x;
  const int kc = tid >> 6, lane = tid & 63;
  const int quad = lane >> 4, col = lane & 15;
  const float* src;
  float scale = 1.0f;
  if (tile < 8) {
    src = wq + (tile * 16 + col) * D_;
    scale = 0.25f * LOG2E;  // DH^-0.5 and log2e folded into W_q
  } else if (tile < 16) {
    src = wmem + ((tile - 8) * 16 + col) * D_;
  } else {
    src = wmem + (128 + (tile - 16) * 16 + col) * D_;
  }
  const float* p = src + kc * 32 + quad * 8;
  bf16x8 w;
#pragma unroll
  for (int j = 0; j < 8; ++j) w[j] = (__bf16)(p[j] * scale);
  *(bf16x8*)(Wb + ((size_t)((tile * 4 + kc) * 64) + lane) * 8) = w;
}

// ---------------------------------------------------------------------------
// Projection (round-8, unchanged): 16 l-rows/block, 4 waves x 6 tiles.
// Qs natural; Ks tau-permuted (key bits 2<->3 swapped); V^T with mask folded:
// Vp[bh][tile][row][col]: rows 0-15 = V^T*mask, row 16 = mask (l-sum row),
// rows 17-31 unwritten (harmless garbage).
// ---------------------------------------------------------------------------
__global__ __launch_bounds__(256) void proj_kernel(
    const float* __restrict__ qin, const int* __restrict__ mask,
    const __bf16* __restrict__ Wb, __bf16* __restrict__ Qs,
    __bf16* __restrict__ Ks, __bf16* __restrict__ Vp) {
  __shared__ float xl[16][132];  // row stride >= 128 (D)!
  const int b = blockIdx.x >> 7;
  const int l0 = (blockIdx.x & 127) * 16;
  const int tid = threadIdx.x;

#pragma unroll
  for (int i = 0; i < 2; ++i) {
    int idx = i * 256 + tid;
    int d = idx >> 2;
    int l4 = (idx & 3) * 4;
    const float4 v = *(const float4*)&qin[(b * D_ + d) * L_ + l0 + l4];
    xl[l4 + 0][d] = v.x;
    xl[l4 + 1][d] = v.y;
    xl[l4 + 2][d] = v.z;
    xl[l4 + 3][d] = v.w;
  }

  // Mask row 16 of each head's Vp tile for our 16 columns.
  if (tid < 128) {
    const int hh = tid >> 4, c = tid & 15;
    const float mv = (float)mask[b * L_ + l0 + c];
    __bf16* dst = Vp +
        (((size_t)(b * H_ + hh) * 64 + (l0 >> 5)) * 32 + 16) * 32 +
        (l0 & 31) + c;
    *dst = (__bf16)mv;
  }
  __syncthreads();

  const int lane = tid & 63, wave = tid >> 6;
  const int quad = lane >> 4, col = lane & 15;

  bf16x8 af[4];
#pragma unroll
  for (int kc = 0; kc < 4; ++kc) {
    const float* s = &xl[col][kc * 32 + quad * 8];
#pragma unroll
    for (int j = 0; j < 8; ++j) af[kc][j] = (__bf16)s[j];
  }

  const int lbase = l0 + quad * 4;                       // Q rows
  const int quadK = ((quad & 1) << 1) | (quad >> 1);     // tau: swap bits 2,3
  const int lbaseK = l0 + quadK * 4;                     // K rows (permuted)
  const float mvv = (float)mask[b * L_ + l0 + col];      // V column mask

#pragma unroll
  for (int tt = 0; tt < 6; ++tt) {
    const int tile = wave * 6 + tt;
    floatx4 acc = {0.f, 0.f, 0.f, 0.f};
    const bool isV = (tile >= 16);
#pragma unroll
    for (int kc = 0; kc < 4; ++kc) {
      bf16x8 wf =
          *(const bf16x8*)(Wb + ((size_t)((tile * 4 + kc) * 64) + lane) * 8);
      acc = isV ? __builtin_amdgcn_mfma_f32_16x16x32_bf16(wf, af[kc], acc, 0, 0, 0)
                : __builtin_amdgcn_mfma_f32_16x16x32_bf16(af[kc], wf, acc, 0, 0, 0);
    }
    if (tile < 8) {  // Q head
      __bf16* dst = Qs + ((size_t)((b * H_ + tile) * L_) + lbase) * DH_ + col;
#pragma unroll
      for (int r = 0; r < 4; ++r) dst[r * DH_] = (__bf16)acc[r];
    } else if (tile < 16) {  // K head, tau-permuted rows
      __bf16* dst =
          Ks + ((size_t)((b * H_ + tile - 8) * L_) + lbaseK) * DH_ + col;
#pragma unroll
      for (int r = 0; r < 4; ++r) dst[r * DH_] = (__bf16)acc[r];
    } else {  // V^T * mask
      __bf16* dst = Vp +
          (((size_t)(b * H_ + (tile - 16)) * 64 + (l0 >> 5)) * 32 + quad * 4) * 32 +
          (l0 & 31) + col;
#pragma unroll
      for (int r = 0; r < 4; ++r) dst[r * 32] = (__bf16)(acc[r] * mvv);
    }
  }
}

// ---------------------------------------------------------------------------
// Attention v10 = v9 (K-split wave pairs, XCD remap) + rotated-S software
// pipeline.
//   Post-mortem v9: VGPR_Count is granules-of-4 -> v9 ran 128 VGPR = 4
//   waves/SIMD (not 8), and the single-chain loop serialized each wave on
//   S-MFMA latency -> exp -> PV. Per-SIMD cost ~456 cyc/tile vs ~170 cyc of
//   VALU work.
//   v10 pipeline (iteration t):
//     1. s_next = MFMA(kf[t+1], qf)        // result consumed NEXT iter
//     2. pA/pB  = exp2+cvt(s)              // s = S(t), MFMA'd one iter ago
//     3. acc   += PV(v0[t]) + PV(v1[t])    // v loaded >=1.5 iters ago
//     4. reload buf[t&1] with tile t+2     // regs dead after steps 1/3
//     5. s = s_next
//   -> MFMA result latency and L2 load latency both hidden behind one full
//   iteration (~190 cyc) of independent work; trans pipe (16 v_exp_f32/tile)
//   becomes the binding resource. Cost vs v9: +16 VGPR for the extra live s.
// grid = B*H*(L/64) = 2048 blocks x 4 waves (each wave: 32 q x 32 kv-tiles).
// ---------------------------------------------------------------------------
__global__ __launch_bounds__(256, 4) void attn_kernel(
    const __bf16* __restrict__ Qs, const __bf16* __restrict__ Ks,
    const __bf16* __restrict__ Vp, float* __restrict__ out) {
  __shared__ float red[2][64][17];  // stride 17 floats: conflict-free lane-major
  const int idx = blockIdx.x;
  const int qb = idx >> 6;        // 32 q-blocks of 64 rows
  const int bhi = idx & 63;       // bh minor -> idx%8 = h fixed per bh
  const int h = bhi & 7;
  const int b = bhi >> 3;
  const int tid = threadIdx.x;
  const int lane = tid & 63, wave = tid >> 6;
  const int pair = wave >> 1;     // which 32 q-rows of this block
  const int half = wave & 1;      // which 32 KV tiles
  const int n = lane & 31, hh = lane >> 5;
  const int q0 = qb * 64 + pair * 32;
  const size_t bh = (size_t)(b * H_ + h);

  // Q B-frag: B[k=dh=8*hh+j][n=q]
  const bf16x8 qf = *(const bf16x8*)(Qs + (bh * L_ + q0 + n) * DH_ + 8 * hh);

  const __bf16* Kp = Ks + bh * L_ * DH_ + (size_t)n * DH_ + 8 * hh +
                     (size_t)(half * 32) * 32 * DH_;
  const __bf16* Vq = Vp + (bh * 64 * 32 + (size_t)n) * 32 + 8 * hh +
                     (size_t)(half * 32) * 1024;

  floatx16 acc;
#pragma unroll
  for (int r = 0; r < 16; ++r) acc[r] = 0.f;
  const floatx16 zz = acc;

  // prologue: double-buffer tiles 0 and 1; S(0) in flight.
  bf16x8 kf[2], v0[2], v1[2];
  kf[0] = *(const bf16x8*)(Kp);
  v0[0] = *(const bf16x8*)(Vq);
  v1[0] = *(const bf16x8*)(Vq + 16);
  kf[1] = *(const bf16x8*)(Kp + 32 * DH_);
  v0[1] = *(const bf16x8*)(Vq + 1024);
  v1[1] = *(const bf16x8*)(Vq + 1024 + 16);
  floatx16 s = __builtin_amdgcn_mfma_f32_32x32x16_bf16(kf[0], qf, zz, 0, 0, 0);

#pragma unroll 2
  for (int t = 0; t < 32; ++t) {
    const int cur = t & 1, nxt = cur ^ 1;
    // 1. S(t+1) issued now, consumed next iteration (latency hidden).
    //    (t=31: computes junk S(clamped tile), never consumed.)
    floatx16 sn =
        __builtin_amdgcn_mfma_f32_32x32x16_bf16(kf[nxt], qf, zz, 0, 0, 0);
    // 2. P^T(t) = exp2(S(t)): packed pairs are exactly the PV B-frags.
    bf16x8 pA, pB;
#pragma unroll
    for (int j = 0; j < 8; ++j) pA[j] = (__bf16)EXP2(s[j]);
#pragma unroll
    for (int j = 0; j < 8; ++j) pB[j] = (__bf16)EXP2(s[8 + j]);
    // 3. PV(t).
    acc = __builtin_amdgcn_mfma_f32_32x32x16_bf16(v0[cur], pA, acc, 0, 0, 0);
    acc = __builtin_amdgcn_mfma_f32_32x32x16_bf16(v1[cur], pB, acc, 0, 0, 0);
    // 4. reload freed buffer with tile t+2 (clamped redundant load at tail).
    const int tn = (t + 2 < 32) ? t + 2 : t;
    kf[cur] = *(const bf16x8*)(Kp + (size_t)tn * 32 * DH_);
    v0[cur] = *(const bf16x8*)(Vq + (size_t)tn * 1024);
    v1[cur] = *(const bf16x8*)(Vq + (size_t)tn * 1024 + 16);
    // 5. rotate.
    s = sn;
  }

  // cross-wave K-reduction: half 0 parks its partial acc in LDS, half 1 sums.
  if (half == 0) {
#pragma unroll
    for (int r = 0; r < 16; ++r) red[pair][lane][r] = acc[r];
  }
  __syncthreads();
  if (half == 0) return;
#pragma unroll
  for (int r = 0; r < 16; ++r) acc[r] += red[pair][lane][r];

  // l = row 16 of O^T = acc reg 8 on the hh==0 half; broadcast to hh==1.
  float lmine = acc[8];
  float lother = __shfl_xor(lmine, 32, 64);
  float inv = __builtin_amdgcn_rcpf(hh ? lother : lmine);

  // regs 0-7 are the 8 valid dh rows for this half: dh = (r&3)+8*(r>>2)+4*hh
  float* obase = out + ((size_t)(b * D_ + h * DH_)) * L_ + q0 + n;
#pragma unroll
  for (int r = 0; r < 8; ++r) {
    const int dh = (r & 3) + 8 * (r >> 2) + 4 * hh;
    obase[(size_t)dh * L_] = acc[r] * inv;
  }
}

// ---------------------------------------------------------------------------
extern "C" void kernel_launch(void* const* d_in, const int* in_sizes, int n_in,
                              void* d_out, int out_size, void* d_ws,
                              size_t ws_size, hipStream_t stream) {
  const float* queries = (const float*)d_in[0];  // [B, D, L] fp32
  const int*   mask    = (const int*)d_in[1];    // [B, L] int32
  const float* wmem    = (const float*)d_in[2];  // [2D, D] fp32
  const float* wq      = (const float*)d_in[3];  // [D, D] fp32
  float* out = (float*)d_out;                    // [B, D, L] fp32

  // Workspace: Qs 4 MiB | Ks 4 MiB | Vp 8 MiB.
  const size_t SEG = (size_t)B_ * H_ * L_ * DH_ * sizeof(__bf16);
  __bf16* Qs = (__bf16*)d_ws;
  __bf16* Ks = (__bf16*)((char*)d_ws + SEG);
  __bf16* Vp = (__bf16*)((char*)d_ws + 2 * SEG);

  // Wb (96 KiB) in d_out scratch: wconv writes, proj reads, attn then
  // overwrites ALL of d_out — stream-ordered, race-free.
  __bf16* Wb = (__bf16*)((char*)d_out + (4u << 20));

  wconv_kernel<<<24, 256, 0, stream>>>(wmem, wq, Wb);
  proj_kernel<<<B_ * (L_ / 16), 256, 0, stream>>>(queries, mask, Wb, Qs, Ks, Vp);
  attn_kernel<<<B_ * H_ * (L_ / 64), 256, 0, stream>>>(Qs, Ks, Vp, out);
}

// Round 3
// 111.462 us; speedup vs baseline: 1.0762x; 1.0762x over previous
//
#include <hip/hip_runtime.h>
#include <math.h>

// Problem constants
#define B_  8
#define D_  128
#define L_  2048
#define H_  8
#define DH_ 16

#define LOG2E 1.4426950408889634f

typedef __bf16 bf16x8 __attribute__((ext_vector_type(8)));
typedef float  floatx4 __attribute__((ext_vector_type(4)));
typedef float  floatx16 __attribute__((ext_vector_type(16)));

#if __has_builtin(__builtin_amdgcn_exp2f)
#define EXP2(x) __builtin_amdgcn_exp2f(x)
#else
#define EXP2(x) exp2f(x)
#endif

// ---------------------------------------------------------------------------
// Weight pre-convert: fp32 W -> bf16 MFMA frag layout (lane idx = col,
// k = quad*8+j). tiles 0..7 = Q heads (W_q pre-scaled by DH^-0.5 * log2e so
// attn softmax is exp2(s)), 8..15 = K, 16..23 = V.
// ---------------------------------------------------------------------------
__global__ __launch_bounds__(256) void wconv_kernel(
    const float* __restrict__ wmem, const float* __restrict__ wq,
    __bf16* __restrict__ Wb) {
  const int tile = blockIdx.x;
  const int tid = threadIdx.x;
  const int kc = tid >> 6, lane = tid & 63;
  const int quad = lane >> 4, col = lane & 15;
  const float* src;
  float scale = 1.0f;
  if (tile < 8) {
    src = wq + (tile * 16 + col) * D_;
    scale = 0.25f * LOG2E;  // DH^-0.5 and log2e folded into W_q
  } else if (tile < 16) {
    src = wmem + ((tile - 8) * 16 + col) * D_;
  } else {
    src = wmem + (128 + (tile - 16) * 16 + col) * D_;
  }
  const float* p = src + kc * 32 + quad * 8;
  bf16x8 w;
#pragma unroll
  for (int j = 0; j < 8; ++j) w[j] = (__bf16)(p[j] * scale);
  *(bf16x8*)(Wb + ((size_t)((tile * 4 + kc) * 64) + lane) * 8) = w;
}

// ---------------------------------------------------------------------------
// Projection v2: same math/MFMA structure as round-8, but the epilogue now
// stages all 24 tiles in LDS (tau-permute + mask fold applied at LDS-write
// time) and then does cooperative bf16x8 (16B) coalesced global stores.
//   Post-mortem v10: proj inferred ~40us of the 119us total; old epilogue
//   was ~6k scalar 2B global stores/block -> L2 store-transaction-bound.
//   Q/K per head: 16 rows x 16 cols = 512B CONTIGUOUS in Qs/Ks -> 32 lanes
//   x bf16x8. V per head: 17 rows (incl. mask row 16) x 32B segments.
// ---------------------------------------------------------------------------
__global__ __launch_bounds__(256) void proj_kernel(
    const float* __restrict__ qin, const int* __restrict__ mask,
    const __bf16* __restrict__ Wb, __bf16* __restrict__ Qs,
    __bf16* __restrict__ Ks, __bf16* __restrict__ Vp) {
  __shared__ float xl[16][132];        // row stride >= 128 (D)!
  __shared__ __bf16 Qst[8][16][16];    // [head][l-row][col]
  __shared__ __bf16 Kst[8][16][16];    // [head][tau-permuted l-row][col]
  __shared__ __bf16 Vst[8][17][16];    // [head][dh-row 0-15, mask row 16][l-col]
  const int b = blockIdx.x >> 7;
  const int l0 = (blockIdx.x & 127) * 16;
  const int tid = threadIdx.x;

#pragma unroll
  for (int i = 0; i < 2; ++i) {
    int idx = i * 256 + tid;
    int d = idx >> 2;
    int l4 = (idx & 3) * 4;
    const float4 v = *(const float4*)&qin[(b * D_ + d) * L_ + l0 + l4];
    xl[l4 + 0][d] = v.x;
    xl[l4 + 1][d] = v.y;
    xl[l4 + 2][d] = v.z;
    xl[l4 + 3][d] = v.w;
  }

  // Mask row 16 of each head's Vst tile for our 16 columns.
  if (tid < 128) {
    const int hh = tid >> 4, c = tid & 15;
    Vst[hh][16][c] = (__bf16)(float)mask[b * L_ + l0 + c];
  }
  __syncthreads();

  const int lane = tid & 63, wave = tid >> 6;
  const int quad = lane >> 4, col = lane & 15;

  bf16x8 af[4];
#pragma unroll
  for (int kc = 0; kc < 4; ++kc) {
    const float* s = &xl[col][kc * 32 + quad * 8];
#pragma unroll
    for (int j = 0; j < 8; ++j) af[kc][j] = (__bf16)s[j];
  }

  const int quadK = ((quad & 1) << 1) | (quad >> 1);     // tau: swap bits 2,3
  const float mvv = (float)mask[b * L_ + l0 + col];      // V column mask

#pragma unroll
  for (int tt = 0; tt < 6; ++tt) {
    const int tile = wave * 6 + tt;
    floatx4 acc = {0.f, 0.f, 0.f, 0.f};
    const bool isV = (tile >= 16);
#pragma unroll
    for (int kc = 0; kc < 4; ++kc) {
      bf16x8 wf =
          *(const bf16x8*)(Wb + ((size_t)((tile * 4 + kc) * 64) + lane) * 8);
      acc = isV ? __builtin_amdgcn_mfma_f32_16x16x32_bf16(wf, af[kc], acc, 0, 0, 0)
                : __builtin_amdgcn_mfma_f32_16x16x32_bf16(af[kc], wf, acc, 0, 0, 0);
    }
    if (tile < 8) {  // Q head -> LDS
#pragma unroll
      for (int r = 0; r < 4; ++r) Qst[tile][quad * 4 + r][col] = (__bf16)acc[r];
    } else if (tile < 16) {  // K head, tau-permuted rows -> LDS
#pragma unroll
      for (int r = 0; r < 4; ++r)
        Kst[tile - 8][quadK * 4 + r][col] = (__bf16)acc[r];
    } else {  // V^T * mask -> LDS
#pragma unroll
      for (int r = 0; r < 4; ++r)
        Vst[tile - 16][quad * 4 + r][col] = (__bf16)(acc[r] * mvv);
    }
  }
  __syncthreads();

  // Cooperative coalesced stores.
  {
    const int hID = tid >> 5;           // 0..7
    const int u = tid & 31;             // 0..31
    const int row = u >> 1, ch = (u & 1) * 8;
    const size_t bhq = (size_t)(b * H_ + hID);
    bf16x8 qv = *(const bf16x8*)&Qst[hID][row][ch];
    *(bf16x8*)(Qs + (bhq * L_ + l0 + row) * DH_ + ch) = qv;
    bf16x8 kv = *(const bf16x8*)&Kst[hID][row][ch];
    *(bf16x8*)(Ks + (bhq * L_ + l0 + row) * DH_ + ch) = kv;
  }
  // V: 8 heads x 17 rows x 2 halves = 272 16B units.
#pragma unroll
  for (int pass = 0; pass < 2; ++pass) {
    const int u = pass * 256 + tid;
    if (u < 272) {
      const int hID = u / 34;
      const int w = u - hID * 34;
      const int row = w >> 1, ch = (w & 1) * 8;
      bf16x8 vv = *(const bf16x8*)&Vst[hID][row][ch];
      __bf16* dst = Vp +
          (((size_t)(b * H_ + hID) * 64 + (l0 >> 5)) * 32 + row) * 32 +
          (l0 & 31) + ch;
      *(bf16x8*)dst = vv;
    }
  }
}

// ---------------------------------------------------------------------------
// Attention v11 = dual-q per wave: one K/V tile load feeds TWO 32-row
// q-groups -> K/V register traffic halves (768 MB -> 384 MB through L1/L2).
//   Post-mortem v8-v10: time invariant (48-54us) under occupancy 3->4.7
//   waves/SIMD and pipeline restructures; VALUBusy ~39% with zero bank
//   conflicts -> correlated vmcnt stalls on the contended L1/L2 read path.
//   Traffic is the only knob not yet turned. Loads for tile t+1 are issued
//   at the TOP of iteration t (v10 issued them at the bottom -> distance was
//   only the loop back-edge; now it is a full ~300cyc body).
// K-split-2 across wave pairs kept (exp2-sum is linear in k-tiles -> exact).
// grid = B*H*(L/128) = 1024 blocks x 4 waves
//   wave = (pair, half): pair -> q-rows [qb*128+pair*64, +64), half -> 32
//   KV tiles. Each wave: 64 q x 32 kv-tiles.
// ---------------------------------------------------------------------------
__global__ __launch_bounds__(256, 4) void attn_kernel(
    const __bf16* __restrict__ Qs, const __bf16* __restrict__ Ks,
    const __bf16* __restrict__ Vp, float* __restrict__ out) {
  __shared__ float red[2][64][33];  // 32 parked floats/lane, pad stride 33
  const int idx = blockIdx.x;
  const int qb = idx >> 6;        // 16 q-blocks of 128 rows
  const int bhi = idx & 63;       // bh minor -> idx%8 = h fixed per bh (XCD)
  const int h = bhi & 7;
  const int b = bhi >> 3;
  const int tid = threadIdx.x;
  const int lane = tid & 63, wave = tid >> 6;
  const int pair = wave >> 1;     // which 64 q-rows of this block
  const int half = wave & 1;      // which 32 KV tiles
  const int n = lane & 31, hh = lane >> 5;
  const int q0 = qb * 128 + pair * 64;
  const size_t bh = (size_t)(b * H_ + h);

  // Q B-frags: B[k=dh=8*hh+j][n=q] for q-rows q0+n and q0+32+n
  const bf16x8 qf0 = *(const bf16x8*)(Qs + (bh * L_ + q0 + n) * DH_ + 8 * hh);
  const bf16x8 qf1 =
      *(const bf16x8*)(Qs + (bh * L_ + q0 + 32 + n) * DH_ + 8 * hh);

  const __bf16* Kp = Ks + bh * L_ * DH_ + (size_t)n * DH_ + 8 * hh +
                     (size_t)(half * 32) * 32 * DH_;
  const __bf16* Vq = Vp + (bh * 64 * 32 + (size_t)n) * 32 + 8 * hh +
                     (size_t)(half * 32) * 1024;

  floatx16 acc0, acc1;
#pragma unroll
  for (int r = 0; r < 16; ++r) { acc0[r] = 0.f; acc1[r] = 0.f; }
  const floatx16 zz = acc0;

  // prologue: tile 0 of this wave's half into buffer 0
  bf16x8 kf[2], va[2], vb[2];
  kf[0] = *(const bf16x8*)(Kp);
  va[0] = *(const bf16x8*)(Vq);
  vb[0] = *(const bf16x8*)(Vq + 16);

#pragma unroll 2
  for (int t = 0; t < 32; ++t) {
    const int cur = t & 1, nxt = cur ^ 1;
    // issue next-tile loads FIRST: consumed at top of next iteration ->
    // load->use distance = one full body (~300 cyc), covers L2 latency.
    const int tn = (t + 1 < 32) ? t + 1 : t;
    kf[nxt] = *(const bf16x8*)(Kp + (size_t)tn * 32 * DH_);
    va[nxt] = *(const bf16x8*)(Vq + (size_t)tn * 1024);
    vb[nxt] = *(const bf16x8*)(Vq + (size_t)tn * 1024 + 16);
    // S^T for both q-groups (32 keys x 32 q each), C = 0
    floatx16 s0 = __builtin_amdgcn_mfma_f32_32x32x16_bf16(kf[cur], qf0, zz, 0, 0, 0);
    floatx16 s1 = __builtin_amdgcn_mfma_f32_32x32x16_bf16(kf[cur], qf1, zz, 0, 0, 0);
    // P^T = exp2(S^T): packed pairs are exactly the PV B-frags
    bf16x8 pA0, pB0, pA1, pB1;
#pragma unroll
    for (int j = 0; j < 8; ++j) pA0[j] = (__bf16)EXP2(s0[j]);
#pragma unroll
    for (int j = 0; j < 8; ++j) pB0[j] = (__bf16)EXP2(s0[8 + j]);
#pragma unroll
    for (int j = 0; j < 8; ++j) pA1[j] = (__bf16)EXP2(s1[j]);
#pragma unroll
    for (int j = 0; j < 8; ++j) pB1[j] = (__bf16)EXP2(s1[8 + j]);
    // PV: the SAME V tile feeds both q-groups (this is the traffic halving)
    acc0 = __builtin_amdgcn_mfma_f32_32x32x16_bf16(va[cur], pA0, acc0, 0, 0, 0);
    acc0 = __builtin_amdgcn_mfma_f32_32x32x16_bf16(vb[cur], pB0, acc0, 0, 0, 0);
    acc1 = __builtin_amdgcn_mfma_f32_32x32x16_bf16(va[cur], pA1, acc1, 0, 0, 0);
    acc1 = __builtin_amdgcn_mfma_f32_32x32x16_bf16(vb[cur], pB1, acc1, 0, 0, 0);
  }

  // cross-wave K-reduction: half 0 parks both partial accs, half 1 sums.
  if (half == 0) {
#pragma unroll
    for (int r = 0; r < 16; ++r) {
      red[pair][lane][r] = acc0[r];
      red[pair][lane][16 + r] = acc1[r];
    }
  }
  __syncthreads();
  if (half == 0) return;
#pragma unroll
  for (int r = 0; r < 16; ++r) {
    acc0[r] += red[pair][lane][r];
    acc1[r] += red[pair][lane][16 + r];
  }

  // l = row 16 of O^T = acc reg 8 on the hh==0 half; broadcast to hh==1.
  float l0v = acc0[8];
  float l0o = __shfl_xor(l0v, 32, 64);
  float inv0 = __builtin_amdgcn_rcpf(hh ? l0o : l0v);
  float l1v = acc1[8];
  float l1o = __shfl_xor(l1v, 32, 64);
  float inv1 = __builtin_amdgcn_rcpf(hh ? l1o : l1v);

  // regs 0-7 are the 8 valid dh rows for this half: dh = (r&3)+8*(r>>2)+4*hh
  float* obase = out + ((size_t)(b * D_ + h * DH_)) * L_ + q0 + n;
#pragma unroll
  for (int r = 0; r < 8; ++r) {
    const int dh = (r & 3) + 8 * (r >> 2) + 4 * hh;
    obase[(size_t)dh * L_] = acc0[r] * inv0;
    obase[(size_t)dh * L_ + 32] = acc1[r] * inv1;
  }
}

// ---------------------------------------------------------------------------
extern "C" void kernel_launch(void* const* d_in, const int* in_sizes, int n_in,
                              void* d_out, int out_size, void* d_ws,
                              size_t ws_size, hipStream_t stream) {
  const float* queries = (const float*)d_in[0];  // [B, D, L] fp32
  const int*   mask    = (const int*)d_in[1];    // [B, L] int32
  const float* wmem    = (const float*)d_in[2];  // [2D, D] fp32
  const float* wq      = (const float*)d_in[3];  // [D, D] fp32
  float* out = (float*)d_out;                    // [B, D, L] fp32

  // Workspace: Qs 4 MiB | Ks 4 MiB | Vp 8 MiB.
  const size_t SEG = (size_t)B_ * H_ * L_ * DH_ * sizeof(__bf16);
  __bf16* Qs = (__bf16*)d_ws;
  __bf16* Ks = (__bf16*)((char*)d_ws + SEG);
  __bf16* Vp = (__bf16*)((char*)d_ws + 2 * SEG);

  // Wb (96 KiB) in d_out scratch: wconv writes, proj reads, attn then
  // overwrites ALL of d_out — stream-ordered, race-free.
  __bf16* Wb = (__bf16*)((char*)d_out + (4u << 20));

  wconv_kernel<<<24, 256, 0, stream>>>(wmem, wq, Wb);
  proj_kernel<<<B_ * (L_ / 16), 256, 0, stream>>>(queries, mask, Wb, Qs, Ks, Vp);
  attn_kernel<<<B_ * H_ * (L_ / 128), 256, 0, stream>>>(Qs, Ks, Vp, out);
}